// Round 1
// baseline (5122.672 us; speedup 1.0000x reference)
//
#include <hip/hip_runtime.h>
#include <math.h>

namespace {

constexpr int kB   = 8;
constexpr int kL   = 256;
constexpr int kTok = 2048;   // B*L
constexpr int kDM  = 384;
constexpr int kDI  = 768;
constexpr int kDS  = 16;
constexpr int kDTR = 24;
constexpr int kPROJ = 56;    // DTR + 2*DS
constexpr int kNL  = 12;

__device__ __forceinline__ float softplus_f(float x) {
  return (x > 20.f) ? x : log1pf(__expf(x));
}
__device__ __forceinline__ float silu_f(float x) {
  return x / (1.f + __expf(-x));
}

// ---------------- im2col: x [8,512,128] -> patches [2048,256] ----------------
__global__ __launch_bounds__(256) void im2col_k(
    const float* __restrict__ x, float* __restrict__ patches) {
  int token = blockIdx.x;
  int tid = threadIdx.x;
  int b = token >> 8, l = token & 255;
  int h = l >> 3, w = l & 7;
  int p = tid >> 4, q = tid & 15;
  patches[token * 256 + tid] = x[((b * 512) + h * 16 + p) * 128 + w * 16 + q];
}

// ---------------- add positional embedding ----------------
__global__ __launch_bounds__(384) void addpos_k(
    float* __restrict__ tok, const float* __restrict__ pos) {
  int t = blockIdx.x, d = threadIdx.x;
  tok[t * kDM + d] += pos[(t & 255) * kDM + d];
}

// ---------------- layernorm over DM=384, one block per token ----------------
__global__ __launch_bounds__(384) void ln_k(
    const float* __restrict__ in, float* __restrict__ out,
    const float* __restrict__ g, const float* __restrict__ bb) {
  int t = blockIdx.x, d = threadIdx.x;
  float v = in[t * kDM + d];
  float s = v, s2 = v * v;
  #pragma unroll
  for (int m = 32; m >= 1; m >>= 1) {
    s  += __shfl_xor(s, m);
    s2 += __shfl_xor(s2, m);
  }
  __shared__ float ps[6], ps2[6];
  if ((d & 63) == 0) { ps[d >> 6] = s; ps2[d >> 6] = s2; }
  __syncthreads();
  float S = 0.f, S2 = 0.f;
  #pragma unroll
  for (int i = 0; i < 6; ++i) { S += ps[i]; S2 += ps2[i]; }
  float mean = S * (1.f / 384.f);
  float var  = S2 * (1.f / 384.f) - mean * mean;
  float r = rsqrtf(var + 1e-5f);
  out[t * kDM + d] = (v - mean) * r * g[d] + bb[d];
}

// ---------------- tiled SGEMM: C[M,N] (+)= A[M,K] * B[N,K]^T ----------------
// M must be a multiple of 64 (always 2048 here). N, K arbitrary.
// EP: 0 none, 1 softplus(acc+bias). BETA: 1 -> accumulate into C.
// SPLITK>1: gridDim.z K-chunks, atomicAdd epilogue (C must be pre-zeroed;
// bias/EP/BETA must be trivial in that path).
template <int EP, int BETA, int SPLITK>
__global__ __launch_bounds__(256) void sgemm_nt_k(
    const float* __restrict__ A, int lda,
    const float* __restrict__ B, int ldb,
    float* __restrict__ C, int ldc,
    int N, int K, const float* __restrict__ bias) {
  __shared__ float As[16][68];
  __shared__ float Bs[16][68];
  int tid = threadIdx.x;
  int bm = blockIdx.y * 64;
  int bn = blockIdx.x * 64;
  int lr = tid >> 2;          // 0..63 row within staging tile
  int lk = (tid & 3) << 2;    // 0,4,8,12
  int tm = (tid >> 4) << 2;   // 0..60
  int tn = (tid & 15) << 2;   // 0..60
  int k_begin = 0, k_end = K;
  if (SPLITK > 1) {
    int kc = K / SPLITK;
    k_begin = blockIdx.z * kc;
    k_end = k_begin + kc;
  }
  float acc[4][4] = {};
  for (int k0 = k_begin; k0 < k_end; k0 += 16) {
    const float* ap = A + (bm + lr) * lda + k0 + lk;
    #pragma unroll
    for (int j = 0; j < 4; ++j)
      As[lk + j][lr] = (k0 + lk + j < k_end) ? ap[j] : 0.f;
    int col = bn + lr;
    const float* bp = B + col * ldb + k0 + lk;
    #pragma unroll
    for (int j = 0; j < 4; ++j)
      Bs[lk + j][lr] = (col < N && (k0 + lk + j < k_end)) ? bp[j] : 0.f;
    __syncthreads();
    #pragma unroll
    for (int k = 0; k < 16; ++k) {
      float4 a = *(const float4*)&As[k][tm];
      float4 b = *(const float4*)&Bs[k][tn];
      acc[0][0] = fmaf(a.x, b.x, acc[0][0]);
      acc[0][1] = fmaf(a.x, b.y, acc[0][1]);
      acc[0][2] = fmaf(a.x, b.z, acc[0][2]);
      acc[0][3] = fmaf(a.x, b.w, acc[0][3]);
      acc[1][0] = fmaf(a.y, b.x, acc[1][0]);
      acc[1][1] = fmaf(a.y, b.y, acc[1][1]);
      acc[1][2] = fmaf(a.y, b.z, acc[1][2]);
      acc[1][3] = fmaf(a.y, b.w, acc[1][3]);
      acc[2][0] = fmaf(a.z, b.x, acc[2][0]);
      acc[2][1] = fmaf(a.z, b.y, acc[2][1]);
      acc[2][2] = fmaf(a.z, b.z, acc[2][2]);
      acc[2][3] = fmaf(a.z, b.w, acc[2][3]);
      acc[3][0] = fmaf(a.w, b.x, acc[3][0]);
      acc[3][1] = fmaf(a.w, b.y, acc[3][1]);
      acc[3][2] = fmaf(a.w, b.z, acc[3][2]);
      acc[3][3] = fmaf(a.w, b.w, acc[3][3]);
    }
    __syncthreads();
  }
  #pragma unroll
  for (int i = 0; i < 4; ++i) {
    int row = bm + tm + i;
    #pragma unroll
    for (int j = 0; j < 4; ++j) {
      int col = bn + tn + j;
      if (col < N) {
        float v = acc[i][j];
        if (SPLITK > 1) {
          atomicAdd(&C[row * ldc + col], v);
        } else {
          if (bias) v += bias[col];
          if (EP == 1) v = softplus_f(v);
          if (BETA) v += C[row * ldc + col];
          C[row * ldc + col] = v;
        }
      }
    }
  }
}

__global__ __launch_bounds__(256) void zero_k(float* __restrict__ p, int n) {
  int i = blockIdx.x * 256 + threadIdx.x;
  if (i < n) p[i] = 0.f;
}

// ---------------- causal depthwise conv (DC=4) + SiLU ----------------
// u_in = xz[:, :768]; out -> ubuf [2048,768]
__global__ __launch_bounds__(256) void conv_silu_k(
    const float* __restrict__ xz, const float* __restrict__ cw,
    const float* __restrict__ cb, float* __restrict__ u) {
  int d = blockIdx.x * 256 + threadIdx.x;  // < 768
  int t = blockIdx.y;                      // token
  int l = t & 255;
  float acc = cb[d];
  #pragma unroll
  for (int k = 0; k < 4; ++k) {
    int ll = l - 3 + k;
    if (ll >= 0) acc = fmaf(xz[(t - 3 + k) * (2 * kDI) + d], cw[d * 4 + k], acc);
  }
  u[t * kDI + d] = silu_f(acc);
}

// ---------------- selective scan: one thread per (b, d, n) -----------------
// 16 lanes (one per state n) shuffle-reduce the C-dot each step.
// Writes y = (scan_out + u*Dskip) * silu(z).
__global__ __launch_bounds__(256) void scan_k(
    const float* __restrict__ delta, const float* __restrict__ u,
    const float* __restrict__ proj, const float* __restrict__ xz,
    const float* __restrict__ A_log, const float* __restrict__ Dsk,
    float* __restrict__ y) {
  int g = blockIdx.x * 256 + threadIdx.x;  // 0 .. 98303
  int n = g & 15;
  int bd = g >> 4;
  int d = bd % kDI;
  int b = bd / kDI;
  float Aval = -__expf(A_log[d * kDS + n]);
  float Dv = Dsk[d];
  float h = 0.f;
  const float* dp = delta + (b * kL) * kDI + d;
  const float* up = u + (b * kL) * kDI + d;
  const float* pp = proj + (b * kL) * kPROJ;
  const float* zp = xz + (b * kL) * (2 * kDI) + kDI + d;
  float* yp = y + (b * kL) * kDI + d;
  for (int l = 0; l < kL; ++l) {
    float dl = dp[l * kDI];
    float uv = up[l * kDI];
    float Bv = pp[l * kPROJ + kDTR + n];
    float Cv = pp[l * kPROJ + kDTR + kDS + n];
    h = fmaf(__expf(dl * Aval), h, (dl * uv) * Bv);
    float yv = h * Cv;
    yv += __shfl_xor(yv, 1);
    yv += __shfl_xor(yv, 2);
    yv += __shfl_xor(yv, 4);
    yv += __shfl_xor(yv, 8);
    if (n == 0) {
      float z = zp[l * (2 * kDI)];
      yp[l * kDI] = (yv + uv * Dv) * silu_f(z);
    }
  }
}

// ---------------- mean pool over L ----------------
__global__ __launch_bounds__(384) void pool_k(
    const float* __restrict__ h, float* __restrict__ pooled) {
  int b = blockIdx.x, d = threadIdx.x;
  float acc = 0.f;
  for (int l = 0; l < kL; ++l) acc += h[(b * kL + l) * kDM + d];
  pooled[b * kDM + d] = acc * (1.f / 256.f);
}

// ---------------- head: out[b,c] = pooled[b,:] . head_w[c,:] + head_b ------
__global__ __launch_bounds__(64) void head_k(
    const float* __restrict__ pooled, const float* __restrict__ hw,
    const float* __restrict__ hb, float* __restrict__ out) {
  int b = blockIdx.x >> 2, c = blockIdx.x & 3;
  int lane = threadIdx.x;
  float acc = 0.f;
  for (int dd = lane; dd < kDM; dd += 64)
    acc = fmaf(pooled[b * kDM + dd], hw[c * kDM + dd], acc);
  #pragma unroll
  for (int m = 32; m >= 1; m >>= 1) acc += __shfl_xor(acc, m);
  if (lane == 0) out[b * 4 + c] = acc + hb[c];
}

}  // namespace

extern "C" void kernel_launch(void* const* d_in, const int* in_sizes, int n_in,
                              void* d_out, int out_size, void* d_ws, size_t ws_size,
                              hipStream_t stream) {
  (void)in_sizes; (void)n_in; (void)out_size; (void)ws_size;
  const float* x        = (const float*)d_in[0];
  const float* patch_w  = (const float*)d_in[1];
  const float* patch_b  = (const float*)d_in[2];
  const float* pos      = (const float*)d_in[3];
  const float* ln_g     = (const float*)d_in[4];
  const float* ln_b     = (const float*)d_in[5];
  const float* in_w     = (const float*)d_in[6];
  const float* conv_w   = (const float*)d_in[7];
  const float* conv_b   = (const float*)d_in[8];
  const float* xproj_w  = (const float*)d_in[9];
  const float* dtproj_w = (const float*)d_in[10];
  const float* dtproj_b = (const float*)d_in[11];
  const float* A_log    = (const float*)d_in[12];
  const float* Dskip    = (const float*)d_in[13];
  const float* out_w    = (const float*)d_in[14];
  const float* fn_g     = (const float*)d_in[15];
  const float* fn_b     = (const float*)d_in[16];
  const float* head_w   = (const float*)d_in[17];
  const float* head_b   = (const float*)d_in[18];
  float* out = (float*)d_out;

  float* ws = (float*)d_ws;
  float* patches = ws; ws += kTok * 256;       // 524288
  float* tok     = ws; ws += kTok * kDM;       // 786432
  float* hbuf    = ws; ws += kTok * kDM;       // 786432
  float* xz      = ws; ws += kTok * 2 * kDI;   // 3145728
  float* ubuf    = ws; ws += kTok * kDI;       // 1572864
  float* proj    = ws; ws += kTok * kPROJ;     // 114688
  float* delta   = ws; ws += kTok * kDI;       // 1572864
  float* ybuf    = ws; ws += kTok * kDI;       // 1572864
  float* pooled  = ws; ws += kB * kDM;         // 3072   (total ~40.3 MB)

  // Patch embedding: im2col + GEMM(+patch_b) + pos_embed
  im2col_k<<<kTok, 256, 0, stream>>>(x, patches);
  sgemm_nt_k<0, 0, 1><<<dim3(6, 32), 256, 0, stream>>>(
      patches, 256, patch_w, 256, tok, kDM, kDM, 256, patch_b);
  addpos_k<<<kTok, kDM, 0, stream>>>(tok, pos);

  for (int layer = 0; layer < kNL; ++layer) {
    // LN
    ln_k<<<kTok, kDM, 0, stream>>>(tok, hbuf, ln_g + layer * kDM, ln_b + layer * kDM);
    // in_proj: [2048,384] x [1536,384]^T -> xz [2048,1536]
    sgemm_nt_k<0, 0, 1><<<dim3(24, 32), 256, 0, stream>>>(
        hbuf, kDM, in_w + (size_t)layer * 2 * kDI * kDM, kDM, xz, 2 * kDI,
        2 * kDI, kDM, nullptr);
    // depthwise causal conv + SiLU -> ubuf
    conv_silu_k<<<dim3(3, kTok), 256, 0, stream>>>(
        xz, conv_w + layer * kDI * 4, conv_b + layer * kDI, ubuf);
    // x_proj: [2048,768] x [56,768]^T -> proj [2048,56]  (split-K for blocks)
    zero_k<<<(kTok * kPROJ + 255) / 256, 256, 0, stream>>>(proj, kTok * kPROJ);
    sgemm_nt_k<0, 0, 4><<<dim3(1, 32, 4), 256, 0, stream>>>(
        ubuf, kDI, xproj_w + layer * kPROJ * kDI, kDI, proj, kPROJ,
        kPROJ, kDI, nullptr);
    // dt_proj + softplus: [2048,24(of 56)] x [768,24]^T -> delta [2048,768]
    sgemm_nt_k<1, 0, 1><<<dim3(12, 32), 256, 0, stream>>>(
        proj, kPROJ, dtproj_w + layer * kDI * kDTR, kDTR, delta, kDI,
        kDI, kDTR, dtproj_b + layer * kDI);
    // selective scan + skip + gate -> ybuf
    scan_k<<<384, 256, 0, stream>>>(
        delta, ubuf, proj, xz, A_log + layer * kDI * kDS,
        Dskip + layer * kDI, ybuf);
    // out_proj + residual: tok += ybuf x [384,768]^T
    sgemm_nt_k<0, 1, 1><<<dim3(6, 32), 256, 0, stream>>>(
        ybuf, kDI, out_w + (size_t)layer * kDM * kDI, kDI, tok, kDM,
        kDM, kDI, nullptr);
  }

  // Final LN, mean pool, head
  ln_k<<<kTok, kDM, 0, stream>>>(tok, hbuf, fn_g, fn_b);
  pool_k<<<kB, kDM, 0, stream>>>(hbuf, pooled);
  head_k<<<kB * 4, 64, 0, stream>>>(pooled, head_w, head_b, out);
}

// Round 2
// 3587.292 us; speedup vs baseline: 1.4280x; 1.4280x over previous
//
#include <hip/hip_runtime.h>
#include <math.h>

namespace {

constexpr int kB   = 8;
constexpr int kL   = 256;
constexpr int kTok = 2048;   // B*L
constexpr int kDM  = 384;
constexpr int kDI  = 768;
constexpr int kDS  = 16;
constexpr int kDTR = 24;
constexpr int kPROJ = 56;    // DTR + 2*DS
constexpr int kNL  = 12;

__device__ __forceinline__ float softplus_f(float x) {
  return (x > 20.f) ? x : log1pf(__expf(x));
}
__device__ __forceinline__ float silu_f(float x) {
  return x / (1.f + __expf(-x));
}

// ---------------- im2col: x [8,512,128] -> patches [2048,256] ----------------
__global__ __launch_bounds__(256) void im2col_k(
    const float* __restrict__ x, float* __restrict__ patches) {
  int token = blockIdx.x;
  int tid = threadIdx.x;
  int b = token >> 8, l = token & 255;
  int h = l >> 3, w = l & 7;
  int p = tid >> 4, q = tid & 15;
  patches[token * 256 + tid] = x[((b * 512) + h * 16 + p) * 128 + w * 16 + q];
}

// ---------------- add positional embedding ----------------
__global__ __launch_bounds__(384) void addpos_k(
    float* __restrict__ tok, const float* __restrict__ pos) {
  int t = blockIdx.x, d = threadIdx.x;
  tok[t * kDM + d] += pos[(t & 255) * kDM + d];
}

// ---------------- layernorm over DM=384, one block per token ----------------
__global__ __launch_bounds__(384) void ln_k(
    const float* __restrict__ in, float* __restrict__ out,
    const float* __restrict__ g, const float* __restrict__ bb) {
  int t = blockIdx.x, d = threadIdx.x;
  float v = in[t * kDM + d];
  float s = v, s2 = v * v;
  #pragma unroll
  for (int m = 32; m >= 1; m >>= 1) {
    s  += __shfl_xor(s, m);
    s2 += __shfl_xor(s2, m);
  }
  __shared__ float ps[6], ps2[6];
  if ((d & 63) == 0) { ps[d >> 6] = s; ps2[d >> 6] = s2; }
  __syncthreads();
  float S = 0.f, S2 = 0.f;
  #pragma unroll
  for (int i = 0; i < 6; ++i) { S += ps[i]; S2 += ps2[i]; }
  float mean = S * (1.f / 384.f);
  float var  = S2 * (1.f / 384.f) - mean * mean;
  float r = rsqrtf(var + 1e-5f);
  out[t * kDM + d] = (v - mean) * r * g[d] + bb[d];
}

// ---------------- tiled SGEMM: C[M,N] (+)= A[M,K] * B[N,K]^T ----------------
template <int EP, int BETA, int SPLITK>
__global__ __launch_bounds__(256) void sgemm_nt_k(
    const float* __restrict__ A, int lda,
    const float* __restrict__ B, int ldb,
    float* __restrict__ C, int ldc,
    int N, int K, const float* __restrict__ bias) {
  __shared__ float As[16][68];
  __shared__ float Bs[16][68];
  int tid = threadIdx.x;
  int bm = blockIdx.y * 64;
  int bn = blockIdx.x * 64;
  int lr = tid >> 2;          // 0..63 row within staging tile
  int lk = (tid & 3) << 2;    // 0,4,8,12
  int tm = (tid >> 4) << 2;   // 0..60
  int tn = (tid & 15) << 2;   // 0..60
  int k_begin = 0, k_end = K;
  if (SPLITK > 1) {
    int kc = K / SPLITK;
    k_begin = blockIdx.z * kc;
    k_end = k_begin + kc;
  }
  float acc[4][4] = {};
  for (int k0 = k_begin; k0 < k_end; k0 += 16) {
    const float* ap = A + (bm + lr) * lda + k0 + lk;
    #pragma unroll
    for (int j = 0; j < 4; ++j)
      As[lk + j][lr] = (k0 + lk + j < k_end) ? ap[j] : 0.f;
    int col = bn + lr;
    const float* bp = B + col * ldb + k0 + lk;
    #pragma unroll
    for (int j = 0; j < 4; ++j)
      Bs[lk + j][lr] = (col < N && (k0 + lk + j < k_end)) ? bp[j] : 0.f;
    __syncthreads();
    #pragma unroll
    for (int k = 0; k < 16; ++k) {
      float4 a = *(const float4*)&As[k][tm];
      float4 b = *(const float4*)&Bs[k][tn];
      acc[0][0] = fmaf(a.x, b.x, acc[0][0]);
      acc[0][1] = fmaf(a.x, b.y, acc[0][1]);
      acc[0][2] = fmaf(a.x, b.z, acc[0][2]);
      acc[0][3] = fmaf(a.x, b.w, acc[0][3]);
      acc[1][0] = fmaf(a.y, b.x, acc[1][0]);
      acc[1][1] = fmaf(a.y, b.y, acc[1][1]);
      acc[1][2] = fmaf(a.y, b.z, acc[1][2]);
      acc[1][3] = fmaf(a.y, b.w, acc[1][3]);
      acc[2][0] = fmaf(a.z, b.x, acc[2][0]);
      acc[2][1] = fmaf(a.z, b.y, acc[2][1]);
      acc[2][2] = fmaf(a.z, b.z, acc[2][2]);
      acc[2][3] = fmaf(a.z, b.w, acc[2][3]);
      acc[3][0] = fmaf(a.w, b.x, acc[3][0]);
      acc[3][1] = fmaf(a.w, b.y, acc[3][1]);
      acc[3][2] = fmaf(a.w, b.z, acc[3][2]);
      acc[3][3] = fmaf(a.w, b.w, acc[3][3]);
    }
    __syncthreads();
  }
  #pragma unroll
  for (int i = 0; i < 4; ++i) {
    int row = bm + tm + i;
    #pragma unroll
    for (int j = 0; j < 4; ++j) {
      int col = bn + tn + j;
      if (col < N) {
        float v = acc[i][j];
        if (SPLITK > 1) {
          atomicAdd(&C[row * ldc + col], v);
        } else {
          if (bias) v += bias[col];
          if (EP == 1) v = softplus_f(v);
          if (BETA) v += C[row * ldc + col];
          C[row * ldc + col] = v;
        }
      }
    }
  }
}

__global__ __launch_bounds__(256) void zero_k(float* __restrict__ p, int n) {
  int i = blockIdx.x * 256 + threadIdx.x;
  if (i < n) p[i] = 0.f;
}

// ---------------- causal depthwise conv (DC=4) + SiLU ----------------
__global__ __launch_bounds__(256) void conv_silu_k(
    const float* __restrict__ xz, const float* __restrict__ cw,
    const float* __restrict__ cb, float* __restrict__ u) {
  int d = blockIdx.x * 256 + threadIdx.x;  // < 768
  int t = blockIdx.y;                      // token
  int l = t & 255;
  float acc = cb[d];
  #pragma unroll
  for (int k = 0; k < 4; ++k) {
    int ll = l - 3 + k;
    if (ll >= 0) acc = fmaf(xz[(t - 3 + k) * (2 * kDI) + d], cw[d * 4 + k], acc);
  }
  u[t * kDI + d] = silu_f(acc);
}

// ---------------- fused chunked selective scan ----------------
// One block per (b, d): 256 threads = (chunk c in [0,16), state n in [0,16)).
// Linear recurrence h_l = a_l h_{l-1} + b_l is associative:
//   Phase 1: each thread scans its 16 local steps with h0=0, keeping
//            h_local[i] and running product ca[i] in registers.
//   Phase 2: LDS combine of 16 chunk summaries -> true chunk-initial h0.
//   Phase 3: h_true = h_local + ca*h0; reduce over n (4 shuffles); gate+store.
__global__ __launch_bounds__(256) void scan_fused_k(
    const float* __restrict__ delta, const float* __restrict__ u,
    const float* __restrict__ proj, const float* __restrict__ xz,
    const float* __restrict__ A_log, const float* __restrict__ Dsk,
    float* __restrict__ y) {
  int d = blockIdx.x;   // 0..767
  int b = blockIdx.y;   // 0..7
  int tid = threadIdx.x;
  int c = tid >> 4;     // chunk
  int n = tid & 15;     // state
  float Aval = -__expf(A_log[d * kDS + n]);

  const float* dp = delta + ((size_t)(b * kL + c * 16)) * kDI + d;
  const float* up = u     + ((size_t)(b * kL + c * 16)) * kDI + d;
  const float* pp = proj  + ((size_t)(b * kL + c * 16)) * kPROJ;

  float h_reg[16], ca_reg[16], cv[16];
  float h = 0.f, ca = 1.f;
  #pragma unroll
  for (int i = 0; i < 16; ++i) {
    float dl = dp[i * kDI];
    float uv = up[i * kDI];
    float Bv = pp[i * kPROJ + kDTR + n];
    cv[i] = pp[i * kPROJ + kDTR + kDS + n];
    float a = __expf(dl * Aval);
    h = fmaf(a, h, (dl * uv) * Bv);
    ca *= a;
    h_reg[i] = h;
    ca_reg[i] = ca;
  }

  __shared__ float sh_h[16][17];
  __shared__ float sh_a[16][17];
  sh_h[c][n] = h;
  sh_a[c][n] = ca;
  __syncthreads();

  float h0 = 0.f;
  for (int j = 0; j < c; ++j) h0 = fmaf(sh_a[j][n], h0, sh_h[j][n]);

  float Dv = Dsk[d];
  float* yp = y + ((size_t)(b * kL + c * 16)) * kDI + d;
  const float* zp = xz + ((size_t)(b * kL + c * 16)) * (2 * kDI) + kDI + d;
  #pragma unroll
  for (int i = 0; i < 16; ++i) {
    float yv = fmaf(ca_reg[i], h0, h_reg[i]) * cv[i];
    yv += __shfl_xor(yv, 1);
    yv += __shfl_xor(yv, 2);
    yv += __shfl_xor(yv, 4);
    yv += __shfl_xor(yv, 8);
    if (n == 0) {
      float uv = up[i * kDI];
      float z = zp[i * (2 * kDI)];
      yp[i * kDI] = (yv + uv * Dv) * silu_f(z);
    }
  }
}

// ---------------- mean pool over L ----------------
__global__ __launch_bounds__(384) void pool_k(
    const float* __restrict__ h, float* __restrict__ pooled) {
  int b = blockIdx.x, d = threadIdx.x;
  float acc = 0.f;
  for (int l = 0; l < kL; ++l) acc += h[(b * kL + l) * kDM + d];
  pooled[b * kDM + d] = acc * (1.f / 256.f);
}

// ---------------- head ----------------
__global__ __launch_bounds__(64) void head_k(
    const float* __restrict__ pooled, const float* __restrict__ hw,
    const float* __restrict__ hb, float* __restrict__ out) {
  int b = blockIdx.x >> 2, c = blockIdx.x & 3;
  int lane = threadIdx.x;
  float acc = 0.f;
  for (int dd = lane; dd < kDM; dd += 64)
    acc = fmaf(pooled[b * kDM + dd], hw[c * kDM + dd], acc);
  #pragma unroll
  for (int m = 32; m >= 1; m >>= 1) acc += __shfl_xor(acc, m);
  if (lane == 0) out[b * 4 + c] = acc + hb[c];
}

}  // namespace

extern "C" void kernel_launch(void* const* d_in, const int* in_sizes, int n_in,
                              void* d_out, int out_size, void* d_ws, size_t ws_size,
                              hipStream_t stream) {
  (void)in_sizes; (void)n_in; (void)out_size; (void)ws_size;
  const float* x        = (const float*)d_in[0];
  const float* patch_w  = (const float*)d_in[1];
  const float* patch_b  = (const float*)d_in[2];
  const float* pos      = (const float*)d_in[3];
  const float* ln_g     = (const float*)d_in[4];
  const float* ln_b     = (const float*)d_in[5];
  const float* in_w     = (const float*)d_in[6];
  const float* conv_w   = (const float*)d_in[7];
  const float* conv_b   = (const float*)d_in[8];
  const float* xproj_w  = (const float*)d_in[9];
  const float* dtproj_w = (const float*)d_in[10];
  const float* dtproj_b = (const float*)d_in[11];
  const float* A_log    = (const float*)d_in[12];
  const float* Dskip    = (const float*)d_in[13];
  const float* out_w    = (const float*)d_in[14];
  const float* fn_g     = (const float*)d_in[15];
  const float* fn_b     = (const float*)d_in[16];
  const float* head_w   = (const float*)d_in[17];
  const float* head_b   = (const float*)d_in[18];
  float* out = (float*)d_out;

  float* ws = (float*)d_ws;
  float* patches = ws; ws += kTok * 256;
  float* tok     = ws; ws += kTok * kDM;
  float* hbuf    = ws; ws += kTok * kDM;
  float* xz      = ws; ws += kTok * 2 * kDI;
  float* ubuf    = ws; ws += kTok * kDI;
  float* proj    = ws; ws += kTok * kPROJ;
  float* delta   = ws; ws += kTok * kDI;
  float* ybuf    = ws; ws += kTok * kDI;
  float* pooled  = ws; ws += kB * kDM;

  // Patch embedding: im2col + GEMM(+patch_b) + pos_embed
  im2col_k<<<kTok, 256, 0, stream>>>(x, patches);
  sgemm_nt_k<0, 0, 1><<<dim3(6, 32), 256, 0, stream>>>(
      patches, 256, patch_w, 256, tok, kDM, kDM, 256, patch_b);
  addpos_k<<<kTok, kDM, 0, stream>>>(tok, pos);

  for (int layer = 0; layer < kNL; ++layer) {
    ln_k<<<kTok, kDM, 0, stream>>>(tok, hbuf, ln_g + layer * kDM, ln_b + layer * kDM);
    // in_proj: [2048,384] x [1536,384]^T -> xz [2048,1536]
    sgemm_nt_k<0, 0, 1><<<dim3(24, 32), 256, 0, stream>>>(
        hbuf, kDM, in_w + (size_t)layer * 2 * kDI * kDM, kDM, xz, 2 * kDI,
        2 * kDI, kDM, nullptr);
    // depthwise causal conv + SiLU -> ubuf
    conv_silu_k<<<dim3(3, kTok), 256, 0, stream>>>(
        xz, conv_w + layer * kDI * 4, conv_b + layer * kDI, ubuf);
    // x_proj: [2048,768] x [56,768]^T -> proj [2048,56]  (split-K)
    zero_k<<<(kTok * kPROJ + 255) / 256, 256, 0, stream>>>(proj, kTok * kPROJ);
    sgemm_nt_k<0, 0, 4><<<dim3(1, 32, 4), 256, 0, stream>>>(
        ubuf, kDI, xproj_w + layer * kPROJ * kDI, kDI, proj, kPROJ,
        kPROJ, kDI, nullptr);
    // dt_proj + softplus -> delta [2048,768]
    sgemm_nt_k<1, 0, 1><<<dim3(12, 32), 256, 0, stream>>>(
        proj, kPROJ, dtproj_w + layer * kDI * kDTR, kDTR, delta, kDI,
        kDI, kDTR, dtproj_b + layer * kDI);
    // fused chunked selective scan + skip + gate -> ybuf
    scan_fused_k<<<dim3(kDI, kB), 256, 0, stream>>>(
        delta, ubuf, proj, xz, A_log + layer * kDI * kDS,
        Dskip + layer * kDI, ybuf);
    // out_proj + residual: tok += ybuf x [384,768]^T
    sgemm_nt_k<0, 1, 1><<<dim3(6, 32), 256, 0, stream>>>(
        ybuf, kDI, out_w + (size_t)layer * kDM * kDI, kDI, tok, kDM,
        kDM, kDI, nullptr);
  }

  ln_k<<<kTok, kDM, 0, stream>>>(tok, hbuf, fn_g, fn_b);
  pool_k<<<kB, kDM, 0, stream>>>(hbuf, pooled);
  head_k<<<kB * 4, 64, 0, stream>>>(pooled, head_w, head_b, out);
}

// Round 3
// 2362.292 us; speedup vs baseline: 2.1685x; 1.5186x over previous
//
#include <hip/hip_runtime.h>
#include <math.h>

namespace {

constexpr int kB   = 8;
constexpr int kL   = 256;
constexpr int kTok = 2048;   // B*L
constexpr int kDM  = 384;
constexpr int kDI  = 768;
constexpr int kDS  = 16;
constexpr int kDTR = 24;
constexpr int kPROJ = 56;    // DTR + 2*DS
constexpr int kNL  = 12;

__device__ __forceinline__ float softplus_f(float x) {
  return (x > 20.f) ? x : log1pf(__expf(x));
}
__device__ __forceinline__ float silu_f(float x) {
  return x / (1.f + __expf(-x));
}

// ---------------- im2col: x [8,512,128] -> patches [2048,256] ----------------
__global__ __launch_bounds__(256) void im2col_k(
    const float* __restrict__ x, float* __restrict__ patches) {
  int token = blockIdx.x;
  int tid = threadIdx.x;
  int b = token >> 8, l = token & 255;
  int h = l >> 3, w = l & 7;
  int p = tid >> 4, q = tid & 15;
  patches[token * 256 + tid] = x[((b * 512) + h * 16 + p) * 128 + w * 16 + q];
}

// ---------------- add positional embedding ----------------
__global__ __launch_bounds__(384) void addpos_k(
    float* __restrict__ tok, const float* __restrict__ pos) {
  int t = blockIdx.x, d = threadIdx.x;
  tok[t * kDM + d] += pos[(t & 255) * kDM + d];
}

// ---------------- layernorm over DM=384, one block per token ----------------
__global__ __launch_bounds__(384) void ln_k(
    const float* __restrict__ in, float* __restrict__ out,
    const float* __restrict__ g, const float* __restrict__ bb) {
  int t = blockIdx.x, d = threadIdx.x;
  float v = in[t * kDM + d];
  float s = v, s2 = v * v;
  #pragma unroll
  for (int m = 32; m >= 1; m >>= 1) {
    s  += __shfl_xor(s, m);
    s2 += __shfl_xor(s2, m);
  }
  __shared__ float ps[6], ps2[6];
  if ((d & 63) == 0) { ps[d >> 6] = s; ps2[d >> 6] = s2; }
  __syncthreads();
  float S = 0.f, S2 = 0.f;
  #pragma unroll
  for (int i = 0; i < 6; ++i) { S += ps[i]; S2 += ps2[i]; }
  float mean = S * (1.f / 384.f);
  float var  = S2 * (1.f / 384.f) - mean * mean;
  float r = rsqrtf(var + 1e-5f);
  out[t * kDM + d] = (v - mean) * r * g[d] + bb[d];
}

// ------------- 64x64 SGEMM: C[M,N] (+)= A[M,K] * B[N,K]^T -------------------
// ATRANS: A is batched column-major AT[b][K][256] (b = row>>8).
// TRANSC: store C transposed to CT[b][N][256].
// EP==1: softplus(acc+bias). SPLITK>1: atomicAdd (C pre-zeroed).
template <int EP, int SPLITK, int ATRANS, int TRANSC>
__global__ __launch_bounds__(256) void sgemm_nt_k(
    const float* __restrict__ A, int lda,
    const float* __restrict__ B, int ldb,
    float* __restrict__ C, int ldc,
    int N, int K, const float* __restrict__ bias) {
  __shared__ float As[16][68];
  __shared__ float Bs[16][68];
  int tid = threadIdx.x;
  int bm = blockIdx.y * 64;
  int bn = blockIdx.x * 64;
  int lr = tid >> 2;          // 0..63
  int lk = (tid & 3) << 2;    // 0,4,8,12
  int tm = (tid >> 4) << 2;
  int tn = (tid & 15) << 2;
  int k_begin = 0, k_end = K;
  if (SPLITK > 1) {
    int kc = K / SPLITK;
    k_begin = blockIdx.z * kc;
    k_end = k_begin + kc;
  }
  float acc[4][4] = {};
  for (int k0 = k_begin; k0 < k_end; k0 += 16) {
    if (ATRANS) {
      // tile of 64 rows lies in one b; load [k][m] directly, coalesced
      int kk = tid >> 4;          // 0..15
      int m4 = (tid & 15) << 2;   // 0..60
      const float* ap = A + (size_t)(bm >> 8) * (kDI * kL) +
                        (size_t)(k0 + kk) * kL + (bm & 255) + m4;
      float4 av = *(const float4*)ap;
      *(float4*)&As[kk][m4] = av;
    } else {
      const float* ap = A + (size_t)(bm + lr) * lda + k0 + lk;
      #pragma unroll
      for (int j = 0; j < 4; ++j)
        As[lk + j][lr] = (k0 + lk + j < k_end) ? ap[j] : 0.f;
    }
    int col = bn + lr;
    const float* bp = B + (size_t)col * ldb + k0 + lk;
    #pragma unroll
    for (int j = 0; j < 4; ++j)
      Bs[lk + j][lr] = (col < N && (k0 + lk + j < k_end)) ? bp[j] : 0.f;
    __syncthreads();
    #pragma unroll
    for (int k = 0; k < 16; ++k) {
      float4 a = *(const float4*)&As[k][tm];
      float4 b = *(const float4*)&Bs[k][tn];
      acc[0][0] = fmaf(a.x, b.x, acc[0][0]);
      acc[0][1] = fmaf(a.x, b.y, acc[0][1]);
      acc[0][2] = fmaf(a.x, b.z, acc[0][2]);
      acc[0][3] = fmaf(a.x, b.w, acc[0][3]);
      acc[1][0] = fmaf(a.y, b.x, acc[1][0]);
      acc[1][1] = fmaf(a.y, b.y, acc[1][1]);
      acc[1][2] = fmaf(a.y, b.z, acc[1][2]);
      acc[1][3] = fmaf(a.y, b.w, acc[1][3]);
      acc[2][0] = fmaf(a.z, b.x, acc[2][0]);
      acc[2][1] = fmaf(a.z, b.y, acc[2][1]);
      acc[2][2] = fmaf(a.z, b.z, acc[2][2]);
      acc[2][3] = fmaf(a.z, b.w, acc[2][3]);
      acc[3][0] = fmaf(a.w, b.x, acc[3][0]);
      acc[3][1] = fmaf(a.w, b.y, acc[3][1]);
      acc[3][2] = fmaf(a.w, b.z, acc[3][2]);
      acc[3][3] = fmaf(a.w, b.w, acc[3][3]);
    }
    __syncthreads();
  }
  #pragma unroll
  for (int i = 0; i < 4; ++i) {
    int row = bm + tm + i;
    #pragma unroll
    for (int j = 0; j < 4; ++j) {
      int col = bn + tn + j;
      if (col < N) {
        float v = acc[i][j];
        if (SPLITK > 1) {
          atomicAdd(&C[(size_t)row * ldc + col], v);
        } else {
          if (bias) v += bias[col];
          if (EP == 1) v = softplus_f(v);
          if (TRANSC) {
            C[(((size_t)(row >> 8) * kDI + col) << 8) + (row & 255)] = v;
          } else {
            C[(size_t)row * ldc + col] = v;
          }
        }
      }
    }
  }
}

// ------------- 128x64x8 double-buffered SGEMM ------------------------------
// C[M,N] = A * B^T. ATRANS as above. SPLITK>1: atomicAdd epilogue (can target
// a live accumulator like the residual stream).
template <int ATRANS, int SPLITK>
__global__ __launch_bounds__(256) void sgemm128_k(
    const float* __restrict__ A, int lda,
    const float* __restrict__ B, int ldb,
    float* __restrict__ C, int ldc, int K) {
  __shared__ float As[2][8][128];
  __shared__ float Bs[2][8][64];
  int tid = threadIdx.x;
  int bn = blockIdx.x * 64;
  int bm = blockIdx.y * 128;
  int k_begin = 0, kcount = K;
  if (SPLITK > 1) { kcount = K / SPLITK; k_begin = blockIdx.z * kcount; }
  int NK = kcount >> 3;
  int tx = tid & 15, ty = tid >> 4;
  // NT staging coords
  int ra = tid >> 1, ka = (tid & 1) << 2;
  // ATRANS staging coords
  int kat = tid >> 5, mat = (tid & 31) << 2;
  float acc[2][4][4] = {};

  float4 pa, pb;
  // prologue: tile 0
  {
    int k0 = k_begin;
    if (ATRANS) {
      pa = *(const float4*)(A + (size_t)(bm >> 8) * (kDI * kL) +
                            (size_t)(k0 + kat) * kL + (bm & 255) + mat);
    } else {
      pa = *(const float4*)(A + (size_t)(bm + ra) * lda + k0 + ka);
    }
    if (tid < 128)
      pb = *(const float4*)(B + (size_t)(bn + (tid >> 1)) * ldb + k0 + ka);
  }
  if (ATRANS) {
    *(float4*)&As[0][kat][mat] = pa;
  } else {
    As[0][ka + 0][ra] = pa.x; As[0][ka + 1][ra] = pa.y;
    As[0][ka + 2][ra] = pa.z; As[0][ka + 3][ra] = pa.w;
  }
  if (tid < 128) {
    int rb = tid >> 1;
    Bs[0][ka + 0][rb] = pb.x; Bs[0][ka + 1][rb] = pb.y;
    Bs[0][ka + 2][rb] = pb.z; Bs[0][ka + 3][rb] = pb.w;
  }
  __syncthreads();

  int cur = 0;
  for (int kt = 0; kt < NK; ++kt) {
    bool more = (kt + 1 < NK);
    if (more) {
      int k0 = k_begin + (kt + 1) * 8;
      if (ATRANS) {
        pa = *(const float4*)(A + (size_t)(bm >> 8) * (kDI * kL) +
                              (size_t)(k0 + kat) * kL + (bm & 255) + mat);
      } else {
        pa = *(const float4*)(A + (size_t)(bm + ra) * lda + k0 + ka);
      }
      if (tid < 128)
        pb = *(const float4*)(B + (size_t)(bn + (tid >> 1)) * ldb + k0 + ka);
    }
    #pragma unroll
    for (int k = 0; k < 8; ++k) {
      float4 a0 = *(const float4*)&As[cur][k][ty * 4];
      float4 a1 = *(const float4*)&As[cur][k][64 + ty * 4];
      float4 b0 = *(const float4*)&Bs[cur][k][tx * 4];
      float av0[4] = {a0.x, a0.y, a0.z, a0.w};
      float av1[4] = {a1.x, a1.y, a1.z, a1.w};
      float bv[4]  = {b0.x, b0.y, b0.z, b0.w};
      #pragma unroll
      for (int i = 0; i < 4; ++i)
        #pragma unroll
        for (int j = 0; j < 4; ++j) {
          acc[0][i][j] = fmaf(av0[i], bv[j], acc[0][i][j]);
          acc[1][i][j] = fmaf(av1[i], bv[j], acc[1][i][j]);
        }
    }
    if (more) {
      int nxt = cur ^ 1;
      if (ATRANS) {
        *(float4*)&As[nxt][kat][mat] = pa;
      } else {
        As[nxt][ka + 0][ra] = pa.x; As[nxt][ka + 1][ra] = pa.y;
        As[nxt][ka + 2][ra] = pa.z; As[nxt][ka + 3][ra] = pa.w;
      }
      if (tid < 128) {
        int rb = tid >> 1;
        Bs[nxt][ka + 0][rb] = pb.x; Bs[nxt][ka + 1][rb] = pb.y;
        Bs[nxt][ka + 2][rb] = pb.z; Bs[nxt][ka + 3][rb] = pb.w;
      }
    }
    __syncthreads();
    cur ^= 1;
  }

  #pragma unroll
  for (int q = 0; q < 2; ++q) {
    #pragma unroll
    for (int i = 0; i < 4; ++i) {
      int row = bm + q * 64 + ty * 4 + i;
      float* cp = C + (size_t)row * ldc + bn + tx * 4;
      if (SPLITK > 1) {
        atomicAdd(cp + 0, acc[q][i][0]);
        atomicAdd(cp + 1, acc[q][i][1]);
        atomicAdd(cp + 2, acc[q][i][2]);
        atomicAdd(cp + 3, acc[q][i][3]);
      } else {
        *(float4*)cp = make_float4(acc[q][i][0], acc[q][i][1],
                                   acc[q][i][2], acc[q][i][3]);
      }
    }
  }
}

__global__ __launch_bounds__(256) void zero_k(float* __restrict__ p, int n) {
  int i = blockIdx.x * 256 + threadIdx.x;
  if (i < n) p[i] = 0.f;
}

// ------------- causal depthwise conv (DC=4) + SiLU, transposed out ---------
// reads xz[:, :768] (row-major), writes uT[b][d][l]
__global__ __launch_bounds__(256) void conv_tr_k(
    const float* __restrict__ xz, const float* __restrict__ cw,
    const float* __restrict__ cb, float* __restrict__ uT) {
  int b = blockIdx.y;
  int l0 = blockIdx.x * 16;
  int tid = threadIdx.x;
  #pragma unroll
  for (int ch = 0; ch < 3; ++ch) {
    int d = ch * 256 + tid;
    float w0 = cw[d * 4], w1 = cw[d * 4 + 1], w2 = cw[d * 4 + 2], w3 = cw[d * 4 + 3];
    float bias = cb[d];
    float v[19];
    #pragma unroll
    for (int j = 0; j < 19; ++j) {
      int l = l0 - 3 + j;
      v[j] = (l >= 0) ? xz[(size_t)(b * kL + l) * (2 * kDI) + d] : 0.f;
    }
    float* up = uT + ((size_t)b * kDI + d) * kL + l0;
    #pragma unroll
    for (int i = 0; i < 16; ++i) {
      float acc = bias;
      acc = fmaf(v[i], w0, acc);
      acc = fmaf(v[i + 1], w1, acc);
      acc = fmaf(v[i + 2], w2, acc);
      acc = fmaf(v[i + 3], w3, acc);
      up[i] = silu_f(acc);
    }
  }
}

// ------------- fused chunked selective scan, transposed layout -------------
__global__ __launch_bounds__(256) void scan_tr_k(
    const float* __restrict__ deltaT, const float* __restrict__ uT,
    const float* __restrict__ proj, const float* __restrict__ xz,
    const float* __restrict__ A_log, const float* __restrict__ Dsk,
    float* __restrict__ yT) {
  int d = blockIdx.x;   // 0..767
  int b = blockIdx.y;   // 0..7
  int tid = threadIdx.x;
  int c = tid >> 4;     // chunk
  int n = tid & 15;     // state
  __shared__ float sd[256], su[256], sg[256], sy[256];
  __shared__ float sh_h[16][17], sh_a[16][17];
  size_t rbase = ((size_t)b * kDI + d) * kL;
  sd[tid] = deltaT[rbase + tid];
  su[tid] = uT[rbase + tid];
  float zv = xz[(size_t)(b * kL + tid) * (2 * kDI) + kDI + d];
  sg[tid] = silu_f(zv);
  float Aval = -__expf(A_log[d * kDS + n]);
  __syncthreads();

  float h = 0.f, ca = 1.f;
  float h_reg[16], ca_reg[16], cv[16];
  const float* pp = proj + (size_t)(b * kL + c * 16) * kPROJ;
  #pragma unroll
  for (int i = 0; i < 16; ++i) {
    int l = c * 16 + i;
    float dl = sd[l], uv = su[l];
    float Bv = pp[i * kPROJ + kDTR + n];
    cv[i] = pp[i * kPROJ + kDTR + kDS + n];
    float a = __expf(dl * Aval);
    h = fmaf(a, h, (dl * uv) * Bv);
    ca *= a;
    h_reg[i] = h;
    ca_reg[i] = ca;
  }
  sh_h[c][n] = h;
  sh_a[c][n] = ca;
  __syncthreads();

  float h0 = 0.f;
  for (int j = 0; j < c; ++j) h0 = fmaf(sh_a[j][n], h0, sh_h[j][n]);

  float Dv = Dsk[d];
  #pragma unroll
  for (int i = 0; i < 16; ++i) {
    int l = c * 16 + i;
    float yv = fmaf(ca_reg[i], h0, h_reg[i]) * cv[i];
    yv += __shfl_xor(yv, 1);
    yv += __shfl_xor(yv, 2);
    yv += __shfl_xor(yv, 4);
    yv += __shfl_xor(yv, 8);
    if (n == 0) sy[l] = (yv + su[l] * Dv) * sg[l];
  }
  __syncthreads();
  yT[rbase + tid] = sy[tid];
}

// ---------------- mean pool over L ----------------
__global__ __launch_bounds__(384) void pool_k(
    const float* __restrict__ h, float* __restrict__ pooled) {
  int b = blockIdx.x, d = threadIdx.x;
  float acc = 0.f;
  for (int l = 0; l < kL; ++l) acc += h[(b * kL + l) * kDM + d];
  pooled[b * kDM + d] = acc * (1.f / 256.f);
}

// ---------------- head ----------------
__global__ __launch_bounds__(64) void head_k(
    const float* __restrict__ pooled, const float* __restrict__ hw,
    const float* __restrict__ hb, float* __restrict__ out) {
  int b = blockIdx.x >> 2, c = blockIdx.x & 3;
  int lane = threadIdx.x;
  float acc = 0.f;
  for (int dd = lane; dd < kDM; dd += 64)
    acc = fmaf(pooled[b * kDM + dd], hw[c * kDM + dd], acc);
  #pragma unroll
  for (int m = 32; m >= 1; m >>= 1) acc += __shfl_xor(acc, m);
  if (lane == 0) out[b * 4 + c] = acc + hb[c];
}

}  // namespace

extern "C" void kernel_launch(void* const* d_in, const int* in_sizes, int n_in,
                              void* d_out, int out_size, void* d_ws, size_t ws_size,
                              hipStream_t stream) {
  (void)in_sizes; (void)n_in; (void)out_size; (void)ws_size;
  const float* x        = (const float*)d_in[0];
  const float* patch_w  = (const float*)d_in[1];
  const float* patch_b  = (const float*)d_in[2];
  const float* pos      = (const float*)d_in[3];
  const float* ln_g     = (const float*)d_in[4];
  const float* ln_b     = (const float*)d_in[5];
  const float* in_w     = (const float*)d_in[6];
  const float* conv_w   = (const float*)d_in[7];
  const float* conv_b   = (const float*)d_in[8];
  const float* xproj_w  = (const float*)d_in[9];
  const float* dtproj_w = (const float*)d_in[10];
  const float* dtproj_b = (const float*)d_in[11];
  const float* A_log    = (const float*)d_in[12];
  const float* Dskip    = (const float*)d_in[13];
  const float* out_w    = (const float*)d_in[14];
  const float* fn_g     = (const float*)d_in[15];
  const float* fn_b     = (const float*)d_in[16];
  const float* head_w   = (const float*)d_in[17];
  const float* head_b   = (const float*)d_in[18];
  float* out = (float*)d_out;

  float* ws = (float*)d_ws;
  float* tok    = ws; ws += kTok * kDM;
  float* hbuf   = ws; ws += kTok * kDM;
  float* xz     = ws; ws += kTok * 2 * kDI;
  float* uT     = ws; ws += kTok * kDI;
  float* proj   = ws; ws += kTok * kPROJ;
  float* deltaT = ws; ws += kTok * kDI;
  float* yT     = ws; ws += kTok * kDI;
  float* pooled = ws; ws += kB * kDM;
  float* patches = deltaT;  // overlay: patches dead before first dt_proj write

  // Patch embedding: im2col + GEMM(+patch_b) + pos_embed
  im2col_k<<<kTok, 256, 0, stream>>>(x, patches);
  sgemm_nt_k<0, 1, 0, 0><<<dim3(6, 32), 256, 0, stream>>>(
      patches, 256, patch_w, 256, tok, kDM, kDM, 256, patch_b);
  addpos_k<<<kTok, kDM, 0, stream>>>(tok, pos);

  for (int layer = 0; layer < kNL; ++layer) {
    ln_k<<<kTok, kDM, 0, stream>>>(tok, hbuf, ln_g + layer * kDM, ln_b + layer * kDM);
    // in_proj: [2048,384] x [1536,384]^T -> xz [2048,1536]
    sgemm128_k<0, 1><<<dim3(24, 16), 256, 0, stream>>>(
        hbuf, kDM, in_w + (size_t)layer * 2 * kDI * kDM, kDM, xz, 2 * kDI, kDM);
    // depthwise causal conv + SiLU -> uT [b][d][l]
    conv_tr_k<<<dim3(16, kB), 256, 0, stream>>>(
        xz, conv_w + layer * kDI * 4, conv_b + layer * kDI, uT);
    // x_proj: uT^T x [56,768]^T -> proj [2048,56]  (TN, split-K=8, atomics)
    zero_k<<<(kTok * kPROJ + 255) / 256, 256, 0, stream>>>(proj, kTok * kPROJ);
    sgemm_nt_k<0, 8, 1, 0><<<dim3(1, 32, 8), 256, 0, stream>>>(
        uT, 0, xproj_w + layer * kPROJ * kDI, kDI, proj, kPROJ,
        kPROJ, kDI, nullptr);
    // dt_proj + softplus, transposed store -> deltaT [b][d][l]
    sgemm_nt_k<1, 1, 0, 1><<<dim3(12, 32), 256, 0, stream>>>(
        proj, kPROJ, dtproj_w + layer * kDI * kDTR, kDTR, deltaT, 0,
        kDI, kDTR, dtproj_b + layer * kDI);
    // fused chunked selective scan + skip + gate -> yT [b][d][l]
    scan_tr_k<<<dim3(kDI, kB), 256, 0, stream>>>(
        deltaT, uT, proj, xz, A_log + layer * kDI * kDS,
        Dskip + layer * kDI, yT);
    // out_proj + residual: tok += yT^T x [384,768]^T (TN, split-K=2, atomics)
    sgemm128_k<1, 2><<<dim3(6, 16, 2), 256, 0, stream>>>(
        yT, 0, out_w + (size_t)layer * kDM * kDI, kDI, tok, kDM, kDI);
  }

  ln_k<<<kTok, kDM, 0, stream>>>(tok, hbuf, fn_g, fn_b);
  pool_k<<<kB, kDM, 0, stream>>>(hbuf, pooled);
  head_k<<<kB * 4, 64, 0, stream>>>(pooled, head_w, head_b, out);
}

// Round 4
// 1531.765 us; speedup vs baseline: 3.3443x; 1.5422x over previous
//
#include <hip/hip_runtime.h>
#include <math.h>

namespace {

constexpr int kB   = 8;
constexpr int kL   = 256;
constexpr int kTok = 2048;   // B*L
constexpr int kDM  = 384;
constexpr int kDI  = 768;
constexpr int kDS  = 16;
constexpr int kDTR = 24;
constexpr int kPROJ = 56;    // DTR + 2*DS
constexpr int kNL  = 12;

constexpr int kWIN  = 2 * kDI * kDM;   // 589824 in_proj weights/layer
constexpr int kWOUT = kDM * kDI;       // 294912
constexpr int kWX   = kPROJ * kDI;     // 43008
constexpr int kWTOT = kWIN + kWOUT + kWX;  // 927744

typedef float f32x4 __attribute__((ext_vector_type(4)));
typedef short short8 __attribute__((ext_vector_type(8)));

__device__ __forceinline__ float softplus_f(float x) {
  return (x > 20.f) ? x : log1pf(__expf(x));
}
__device__ __forceinline__ float silu_f(float x) {
  return x / (1.f + __expf(-x));
}
__device__ __forceinline__ unsigned short f2bf(float f) {
  union { float f; unsigned u; } v; v.f = f;
  unsigned r = v.u + 0x7FFFu + ((v.u >> 16) & 1u);
  return (unsigned short)(r >> 16);
}

// ---------------- im2col: x [8,512,128] -> patches [2048,256] ----------------
__global__ __launch_bounds__(256) void im2col_k(
    const float* __restrict__ x, float* __restrict__ patches) {
  int token = blockIdx.x;
  int tid = threadIdx.x;
  int b = token >> 8, l = token & 255;
  int h = l >> 3, w = l & 7;
  int p = tid >> 4, q = tid & 15;
  patches[token * 256 + tid] = x[((b * 512) + h * 16 + p) * 128 + w * 16 + q];
}

// ---------------- add positional embedding ----------------
__global__ __launch_bounds__(384) void addpos_k(
    float* __restrict__ tok, const float* __restrict__ pos) {
  int t = blockIdx.x, d = threadIdx.x;
  tok[t * kDM + d] += pos[(t & 255) * kDM + d];
}

// ------------- layernorm over DM=384; BF16OUT: emit bf16 (GEMM A operand) ---
template <bool BF16OUT>
__global__ __launch_bounds__(384) void ln_k(
    const float* __restrict__ in, void* __restrict__ outv,
    const float* __restrict__ g, const float* __restrict__ bb) {
  int t = blockIdx.x, d = threadIdx.x;
  float v = in[t * kDM + d];
  float s = v, s2 = v * v;
  #pragma unroll
  for (int m = 32; m >= 1; m >>= 1) {
    s  += __shfl_xor(s, m);
    s2 += __shfl_xor(s2, m);
  }
  __shared__ float ps[6], ps2[6];
  if ((d & 63) == 0) { ps[d >> 6] = s; ps2[d >> 6] = s2; }
  __syncthreads();
  float S = 0.f, S2 = 0.f;
  #pragma unroll
  for (int i = 0; i < 6; ++i) { S += ps[i]; S2 += ps2[i]; }
  float mean = S * (1.f / 384.f);
  float var  = S2 * (1.f / 384.f) - mean * mean;
  float r = rsqrtf(var + 1e-5f);
  float o = (v - mean) * r * g[d] + bb[d];
  if (BF16OUT) ((unsigned short*)outv)[t * kDM + d] = f2bf(o);
  else ((float*)outv)[t * kDM + d] = o;
}

// ------------- weight cast fp32 -> bf16 (one layer: in | out | x) ----------
__global__ __launch_bounds__(256) void convert_w_k(
    const float* __restrict__ w_in, const float* __restrict__ w_out,
    const float* __restrict__ w_x, unsigned short* __restrict__ dst) {
  int i = blockIdx.x * 256 + threadIdx.x;
  if (i >= kWTOT) return;
  float v;
  if (i < kWIN) v = w_in[i];
  else if (i < kWIN + kWOUT) v = w_out[i - kWIN];
  else v = w_x[i - kWIN - kWOUT];
  dst[i] = f2bf(v);
}

// ------------- bf16 MFMA NT GEMM: C[M,N] fp32 = A[M,K]·B[N,K]^T ------------
// BM=128, BK=32, 256 threads (4 waves). BN in {64,128}.
// EPIL 0: plain store. EPIL 1: atomicAdd with col<N guard (split-K / residual).
// gridDim.z = split-K factor; each z does Kc contiguous k.
template <int BN, int EPIL>
__global__ __launch_bounds__(256) void bgemm_k(
    const unsigned short* __restrict__ A, int lda,
    const unsigned short* __restrict__ B, int ldb,
    float* __restrict__ C, int ldc, int N, int Kc) {
  __shared__ __align__(16) unsigned short As[4][128][8];
  __shared__ __align__(16) unsigned short Bs[4][BN][8];
  int tid = threadIdx.x;
  int bm = blockIdx.y * 128;
  int bn = blockIdx.x * BN;
  int k_begin = blockIdx.z * Kc;
  int wave = tid >> 6, lane = tid & 63;
  int lm = lane & 15, lq = lane >> 4;
  int wm, wn;
  if (BN == 128) { wm = (wave >> 1) * 64; wn = (wave & 1) * 64; }
  else           { wm = wave * 32;        wn = 0; }
  constexpr int MT = (BN == 128) ? 4 : 2;
  f32x4 acc[MT][4] = {};

  for (int kt = 0; kt < Kc; kt += 32) {
    int k0 = k_begin + kt;
    // global loads (16 B each)
    int ar0 = tid & 127, aq0 = tid >> 7;
    int ar1 = ar0, aq1 = aq0 + 2;
    uint4 a0 = *(const uint4*)(A + (size_t)(bm + ar0) * lda + k0 + aq0 * 8);
    uint4 a1 = *(const uint4*)(A + (size_t)(bm + ar1) * lda + k0 + aq1 * 8);
    uint4 b0, b1;
    int br0, bq0, br1 = 0, bq1 = 0;
    if (BN == 128) {
      br0 = tid & 127; bq0 = tid >> 7; br1 = br0; bq1 = bq0 + 2;
      b0 = *(const uint4*)(B + (size_t)(bn + br0) * ldb + k0 + bq0 * 8);
      b1 = *(const uint4*)(B + (size_t)(bn + br1) * ldb + k0 + bq1 * 8);
    } else {
      br0 = tid & 63; bq0 = tid >> 6;
      if (bn + br0 < N)
        b0 = *(const uint4*)(B + (size_t)(bn + br0) * ldb + k0 + bq0 * 8);
      else
        b0 = make_uint4(0u, 0u, 0u, 0u);
    }
    __syncthreads();  // previous iteration's compute done
    *(uint4*)&As[aq0][ar0][0] = a0;
    *(uint4*)&As[aq1][ar1][0] = a1;
    *(uint4*)&Bs[bq0][br0][0] = b0;
    if (BN == 128) *(uint4*)&Bs[bq1][br1][0] = b1;
    __syncthreads();

    short8 bfrag[4];
    #pragma unroll
    for (int ni = 0; ni < 4; ++ni)
      bfrag[ni] = *(const short8*)&Bs[lq][wn + ni * 16 + lm][0];
    #pragma unroll
    for (int mi = 0; mi < MT; ++mi) {
      short8 afrag = *(const short8*)&As[lq][wm + mi * 16 + lm][0];
      #pragma unroll
      for (int ni = 0; ni < 4; ++ni)
        acc[mi][ni] = __builtin_amdgcn_mfma_f32_16x16x32_bf16(
            afrag, bfrag[ni], acc[mi][ni], 0, 0, 0);
    }
  }

  #pragma unroll
  for (int mi = 0; mi < MT; ++mi) {
    #pragma unroll
    for (int ni = 0; ni < 4; ++ni) {
      int grow = bm + wm + mi * 16 + lq * 4;
      int gcol = bn + wn + ni * 16 + lm;
      float* cp = C + (size_t)grow * ldc + gcol;
      #pragma unroll
      for (int r = 0; r < 4; ++r) {
        float v = acc[mi][ni][r];
        if (EPIL == 0) {
          cp[(size_t)r * ldc] = v;
        } else {
          if (gcol < N) atomicAdd(cp + (size_t)r * ldc, v);
        }
      }
    }
  }
}

// ------------- 64x64 fp32 SGEMM (patch embed, dt_proj) ---------------------
// EP==1: softplus(acc+bias). TRANSC: store C transposed CT[b][N][256].
template <int EP, int TRANSC>
__global__ __launch_bounds__(256) void sgemm_nt_k(
    const float* __restrict__ A, int lda,
    const float* __restrict__ B, int ldb,
    float* __restrict__ C, int ldc,
    int N, int K, const float* __restrict__ bias) {
  __shared__ float As[16][68];
  __shared__ float Bs[16][68];
  int tid = threadIdx.x;
  int bm = blockIdx.y * 64;
  int bn = blockIdx.x * 64;
  int lr = tid >> 2;
  int lk = (tid & 3) << 2;
  int tm = (tid >> 4) << 2;
  int tn = (tid & 15) << 2;
  float acc[4][4] = {};
  for (int k0 = 0; k0 < K; k0 += 16) {
    const float* ap = A + (size_t)(bm + lr) * lda + k0 + lk;
    #pragma unroll
    for (int j = 0; j < 4; ++j)
      As[lk + j][lr] = (k0 + lk + j < K) ? ap[j] : 0.f;
    int col = bn + lr;
    const float* bp = B + (size_t)col * ldb + k0 + lk;
    #pragma unroll
    for (int j = 0; j < 4; ++j)
      Bs[lk + j][lr] = (col < N && (k0 + lk + j < K)) ? bp[j] : 0.f;
    __syncthreads();
    #pragma unroll
    for (int k = 0; k < 16; ++k) {
      float4 a = *(const float4*)&As[k][tm];
      float4 b = *(const float4*)&Bs[k][tn];
      float av[4] = {a.x, a.y, a.z, a.w};
      float bv[4] = {b.x, b.y, b.z, b.w};
      #pragma unroll
      for (int i = 0; i < 4; ++i)
        #pragma unroll
        for (int j = 0; j < 4; ++j)
          acc[i][j] = fmaf(av[i], bv[j], acc[i][j]);
    }
    __syncthreads();
  }
  #pragma unroll
  for (int i = 0; i < 4; ++i) {
    int row = bm + tm + i;
    #pragma unroll
    for (int j = 0; j < 4; ++j) {
      int col = bn + tn + j;
      if (col < N) {
        float v = acc[i][j];
        if (bias) v += bias[col];
        if (EP == 1) v = softplus_f(v);
        if (TRANSC) {
          C[(((size_t)(row >> 8) * kDI + col) << 8) + (row & 255)] = v;
        } else {
          C[(size_t)row * ldc + col] = v;
        }
      }
    }
  }
}

__global__ __launch_bounds__(256) void zero_k(float* __restrict__ p, int n) {
  int i = blockIdx.x * 256 + threadIdx.x;
  if (i < n) p[i] = 0.f;
}

// ------------- causal depthwise conv (DC=4) + SiLU --------------------------
// writes uT[b][d][l] fp32 (scan input) and u_bf[token][d] bf16 (x_proj A)
__global__ __launch_bounds__(256) void conv_tr_k(
    const float* __restrict__ xz, const float* __restrict__ cw,
    const float* __restrict__ cb, float* __restrict__ uT,
    unsigned short* __restrict__ u_bf) {
  int b = blockIdx.y;
  int l0 = blockIdx.x * 16;
  int tid = threadIdx.x;
  #pragma unroll
  for (int ch = 0; ch < 3; ++ch) {
    int d = ch * 256 + tid;
    float w0 = cw[d * 4], w1 = cw[d * 4 + 1], w2 = cw[d * 4 + 2], w3 = cw[d * 4 + 3];
    float bias = cb[d];
    float v[19];
    #pragma unroll
    for (int j = 0; j < 19; ++j) {
      int l = l0 - 3 + j;
      v[j] = (l >= 0) ? xz[(size_t)(b * kL + l) * (2 * kDI) + d] : 0.f;
    }
    float* up = uT + ((size_t)b * kDI + d) * kL + l0;
    #pragma unroll
    for (int i = 0; i < 16; ++i) {
      float acc = bias;
      acc = fmaf(v[i], w0, acc);
      acc = fmaf(v[i + 1], w1, acc);
      acc = fmaf(v[i + 2], w2, acc);
      acc = fmaf(v[i + 3], w3, acc);
      float o = silu_f(acc);
      up[i] = o;
      u_bf[(size_t)(b * kL + l0 + i) * kDI + d] = f2bf(o);
    }
  }
}

// ------------- fused chunked selective scan, transposed layout -------------
__global__ __launch_bounds__(256) void scan_tr_k(
    const float* __restrict__ deltaT, const float* __restrict__ uT,
    const float* __restrict__ proj, const float* __restrict__ xz,
    const float* __restrict__ A_log, const float* __restrict__ Dsk,
    float* __restrict__ yT) {
  int d = blockIdx.x;   // 0..767
  int b = blockIdx.y;   // 0..7
  int tid = threadIdx.x;
  int c = tid >> 4;     // chunk
  int n = tid & 15;     // state
  __shared__ float sd[256], su[256], sg[256], sy[256];
  __shared__ float sh_h[16][17], sh_a[16][17];
  size_t rbase = ((size_t)b * kDI + d) * kL;
  sd[tid] = deltaT[rbase + tid];
  su[tid] = uT[rbase + tid];
  float zv = xz[(size_t)(b * kL + tid) * (2 * kDI) + kDI + d];
  sg[tid] = silu_f(zv);
  float Aval = -__expf(A_log[d * kDS + n]);
  __syncthreads();

  float h = 0.f, ca = 1.f;
  float h_reg[16], ca_reg[16], cv[16];
  const float* pp = proj + (size_t)(b * kL + c * 16) * kPROJ;
  #pragma unroll
  for (int i = 0; i < 16; ++i) {
    int l = c * 16 + i;
    float dl = sd[l], uv = su[l];
    float Bv = pp[i * kPROJ + kDTR + n];
    cv[i] = pp[i * kPROJ + kDTR + kDS + n];
    float a = __expf(dl * Aval);
    h = fmaf(a, h, (dl * uv) * Bv);
    ca *= a;
    h_reg[i] = h;
    ca_reg[i] = ca;
  }
  sh_h[c][n] = h;
  sh_a[c][n] = ca;
  __syncthreads();

  float h0 = 0.f;
  for (int j = 0; j < c; ++j) h0 = fmaf(sh_a[j][n], h0, sh_h[j][n]);

  float Dv = Dsk[d];
  #pragma unroll
  for (int i = 0; i < 16; ++i) {
    int l = c * 16 + i;
    float yv = fmaf(ca_reg[i], h0, h_reg[i]) * cv[i];
    yv += __shfl_xor(yv, 1);
    yv += __shfl_xor(yv, 2);
    yv += __shfl_xor(yv, 4);
    yv += __shfl_xor(yv, 8);
    if (n == 0) sy[l] = (yv + su[l] * Dv) * sg[l];
  }
  __syncthreads();
  yT[rbase + tid] = sy[tid];
}

// ------------- transpose yT [b][768][256] fp32 -> y_bf [2048][768] bf16 ----
__global__ __launch_bounds__(256) void transpose_bf_k(
    const float* __restrict__ yT, unsigned short* __restrict__ ybf) {
  int b = blockIdx.z;
  int db = blockIdx.y;   // 12 tiles of 64 d
  int lb = blockIdx.x;   // 4 tiles of 64 l
  __shared__ float tile[64][65];
  int tid = threadIdx.x;
  int lx = tid & 63, dq = tid >> 6;
  const float* src = yT + ((size_t)b * kDI + db * 64) * kL + lb * 64;
  #pragma unroll
  for (int i = 0; i < 16; ++i) {
    int d = dq * 16 + i;
    tile[d][lx] = src[(size_t)d * kL + lx];
  }
  __syncthreads();
  int ly = tid >> 2, dx0 = (tid & 3) * 16;
  unsigned short tmp[16];
  #pragma unroll
  for (int i = 0; i < 16; ++i) tmp[i] = f2bf(tile[dx0 + i][ly]);
  unsigned short* dst =
      ybf + (size_t)(b * kL + lb * 64 + ly) * kDI + db * 64 + dx0;
  *(uint4*)dst = *(const uint4*)tmp;
  *(uint4*)(dst + 8) = *(const uint4*)(tmp + 8);
}

// ---------------- mean pool over L ----------------
__global__ __launch_bounds__(384) void pool_k(
    const float* __restrict__ h, float* __restrict__ pooled) {
  int b = blockIdx.x, d = threadIdx.x;
  float acc = 0.f;
  for (int l = 0; l < kL; ++l) acc += h[(b * kL + l) * kDM + d];
  pooled[b * kDM + d] = acc * (1.f / 256.f);
}

// ---------------- head ----------------
__global__ __launch_bounds__(64) void head_k(
    const float* __restrict__ pooled, const float* __restrict__ hw,
    const float* __restrict__ hb, float* __restrict__ out) {
  int b = blockIdx.x >> 2, c = blockIdx.x & 3;
  int lane = threadIdx.x;
  float acc = 0.f;
  for (int dd = lane; dd < kDM; dd += 64)
    acc = fmaf(pooled[b * kDM + dd], hw[c * kDM + dd], acc);
  #pragma unroll
  for (int m = 32; m >= 1; m >>= 1) acc += __shfl_xor(acc, m);
  if (lane == 0) out[b * 4 + c] = acc + hb[c];
}

}  // namespace

extern "C" void kernel_launch(void* const* d_in, const int* in_sizes, int n_in,
                              void* d_out, int out_size, void* d_ws, size_t ws_size,
                              hipStream_t stream) {
  (void)in_sizes; (void)n_in; (void)out_size; (void)ws_size;
  const float* x        = (const float*)d_in[0];
  const float* patch_w  = (const float*)d_in[1];
  const float* patch_b  = (const float*)d_in[2];
  const float* pos      = (const float*)d_in[3];
  const float* ln_g     = (const float*)d_in[4];
  const float* ln_b     = (const float*)d_in[5];
  const float* in_w     = (const float*)d_in[6];
  const float* conv_w   = (const float*)d_in[7];
  const float* conv_b   = (const float*)d_in[8];
  const float* xproj_w  = (const float*)d_in[9];
  const float* dtproj_w = (const float*)d_in[10];
  const float* dtproj_b = (const float*)d_in[11];
  const float* A_log    = (const float*)d_in[12];
  const float* Dskip    = (const float*)d_in[13];
  const float* out_w    = (const float*)d_in[14];
  const float* fn_g     = (const float*)d_in[15];
  const float* fn_b     = (const float*)d_in[16];
  const float* head_w   = (const float*)d_in[17];
  const float* head_b   = (const float*)d_in[18];
  float* out = (float*)d_out;

  float* ws = (float*)d_ws;
  float* tok    = ws; ws += kTok * kDM;       // 786432
  float* xz     = ws; ws += kTok * 2 * kDI;   // 3145728
  float* uT     = ws; ws += kTok * kDI;       // 1572864
  float* proj   = ws; ws += kTok * kPROJ;     // 114688
  float* deltaT = ws; ws += kTok * kDI;       // 1572864
  float* yT     = ws; ws += kTok * kDI;       // 1572864
  float* pooled = ws; ws += kB * kDM;         // 3072
  unsigned short* w_bf = (unsigned short*)ws; ws += kWTOT / 2;  // 463872 fl
  // overlays (lifetimes verified):
  float* patches       = deltaT;                   // dead before first dt_proj
  unsigned short* h_bf = (unsigned short*)deltaT;  // ln -> in_proj, clobbered by dt_proj
  unsigned short* y_bf = (unsigned short*)deltaT;  // transpose -> out_proj
  unsigned short* u_bf = (unsigned short*)yT;      // conv -> x_proj, clobbered by scan
  float* lnout         = yT;                       // final LN (yT dead)

  // Patch embedding: im2col + fp32 GEMM(+patch_b) + pos_embed
  im2col_k<<<kTok, 256, 0, stream>>>(x, patches);
  sgemm_nt_k<0, 0><<<dim3(6, 32), 256, 0, stream>>>(
      patches, 256, patch_w, 256, tok, kDM, kDM, 256, patch_b);
  addpos_k<<<kTok, kDM, 0, stream>>>(tok, pos);

  for (int layer = 0; layer < kNL; ++layer) {
    // cast this layer's GEMM weights to bf16: [in | out | x]
    convert_w_k<<<(kWTOT + 255) / 256, 256, 0, stream>>>(
        in_w + (size_t)layer * kWIN, out_w + (size_t)layer * kWOUT,
        xproj_w + (size_t)layer * kWX, w_bf);
    // LN -> bf16 A operand
    ln_k<true><<<kTok, kDM, 0, stream>>>(tok, h_bf, ln_g + layer * kDM,
                                         ln_b + layer * kDM);
    // in_proj (MFMA): [2048,384]x[1536,384]^T -> xz fp32
    bgemm_k<128, 0><<<dim3(12, 16, 1), 256, 0, stream>>>(
        h_bf, kDM, w_bf, kDM, xz, 2 * kDI, 2 * kDI, kDM);
    // depthwise causal conv + SiLU -> uT fp32 + u_bf bf16
    conv_tr_k<<<dim3(16, kB), 256, 0, stream>>>(
        xz, conv_w + layer * kDI * 4, conv_b + layer * kDI, uT, u_bf);
    // x_proj (MFMA, split-K=6, atomic): [2048,768]x[56,768]^T -> proj
    zero_k<<<(kTok * kPROJ + 255) / 256, 256, 0, stream>>>(proj, kTok * kPROJ);
    bgemm_k<64, 1><<<dim3(1, 16, 6), 256, 0, stream>>>(
        u_bf, kDI, w_bf + kWIN + kWOUT, kDI, proj, kPROJ, kPROJ, kDI / 6);
    // dt_proj + softplus (fp32), transposed store -> deltaT [b][d][l]
    sgemm_nt_k<1, 1><<<dim3(12, 32), 256, 0, stream>>>(
        proj, kPROJ, dtproj_w + layer * kDI * kDTR, kDTR, deltaT, 0,
        kDI, kDTR, dtproj_b + layer * kDI);
    // fused chunked selective scan + skip + gate -> yT
    scan_tr_k<<<dim3(kDI, kB), 256, 0, stream>>>(
        deltaT, uT, proj, xz, A_log + layer * kDI * kDS,
        Dskip + layer * kDI, yT);
    // transpose+cast yT -> y_bf [2048,768] bf16
    transpose_bf_k<<<dim3(4, 12, kB), 256, 0, stream>>>(yT, y_bf);
    // out_proj (MFMA, split-K=2, atomic into residual): tok += y x W^T
    bgemm_k<128, 1><<<dim3(3, 16, 2), 256, 0, stream>>>(
        y_bf, kDI, w_bf + kWIN, kDI, tok, kDM, kDM, kDI / 2);
  }

  ln_k<false><<<kTok, kDM, 0, stream>>>(tok, lnout, fn_g, fn_b);
  pool_k<<<kB, kDM, 0, stream>>>(lnout, pooled);
  head_k<<<kB * 4, 64, 0, stream>>>(pooled, head_w, head_b, out);
}

// Round 5
// 1363.694 us; speedup vs baseline: 3.7565x; 1.1232x over previous
//
#include <hip/hip_runtime.h>
#include <math.h>

namespace {

constexpr int kB   = 8;
constexpr int kL   = 256;
constexpr int kTok = 2048;   // B*L
constexpr int kDM  = 384;
constexpr int kDI  = 768;
constexpr int kDS  = 16;
constexpr int kDTR = 24;
constexpr int kPROJ = 56;    // DTR + 2*DS
constexpr int kNL  = 12;

constexpr int kWIN  = 2 * kDI * kDM;   // 589824 in_proj weights/layer
constexpr int kWOUT = kDM * kDI;       // 294912
constexpr int kWX   = kPROJ * kDI;     // 43008
constexpr int kWTOT = kWIN + kWOUT + kWX;  // 927744

typedef float f32x4 __attribute__((ext_vector_type(4)));
typedef short short8 __attribute__((ext_vector_type(8)));

__device__ __forceinline__ float softplus_f(float x) {
  return (x > 20.f) ? x : log1pf(__expf(x));
}
__device__ __forceinline__ float silu_f(float x) {
  return x / (1.f + __expf(-x));
}
__device__ __forceinline__ unsigned short f2bf(float f) {
  union { float f; unsigned u; } v; v.f = f;
  unsigned r = v.u + 0x7FFFu + ((v.u >> 16) & 1u);
  return (unsigned short)(r >> 16);
}

// ------------- patch embed GEMM: tok = im2col(x)·patch_w^T + b + pos -------
// A[2048,256] read directly from x; 64x64 fp32 tiles; N=384, K=256.
__global__ __launch_bounds__(256) void patch_gemm_k(
    const float* __restrict__ x, const float* __restrict__ Bw,
    const float* __restrict__ bias, const float* __restrict__ pos,
    float* __restrict__ C) {
  __shared__ float As[16][68];
  __shared__ float Bs[16][68];
  int tid = threadIdx.x;
  int bm = blockIdx.y * 64;
  int bn = blockIdx.x * 64;
  int lr = tid >> 2;
  int lk = (tid & 3) << 2;
  int tm = (tid >> 4) << 2;
  int tn = (tid & 15) << 2;
  float acc[4][4] = {};
  for (int k0 = 0; k0 < 256; k0 += 16) {
    // A stage straight from x: token=bm+lr, cols k0+lk..+3
    {
      int token = bm + lr;
      int b = token >> 8, l = token & 255;
      int h = l >> 3, w = l & 7;
      int p = k0 >> 4;
      const float* ap = x + ((size_t)(b * 512) + h * 16 + p) * 128 + w * 16 + lk;
      float4 av = *(const float4*)ap;
      As[lk + 0][lr] = av.x; As[lk + 1][lr] = av.y;
      As[lk + 2][lr] = av.z; As[lk + 3][lr] = av.w;
    }
    {
      const float* bp = Bw + (size_t)(bn + lr) * 256 + k0 + lk;
      float4 bv = *(const float4*)bp;
      Bs[lk + 0][lr] = bv.x; Bs[lk + 1][lr] = bv.y;
      Bs[lk + 2][lr] = bv.z; Bs[lk + 3][lr] = bv.w;
    }
    __syncthreads();
    #pragma unroll
    for (int k = 0; k < 16; ++k) {
      float4 a = *(const float4*)&As[k][tm];
      float4 b = *(const float4*)&Bs[k][tn];
      float av[4] = {a.x, a.y, a.z, a.w};
      float bv[4] = {b.x, b.y, b.z, b.w};
      #pragma unroll
      for (int i = 0; i < 4; ++i)
        #pragma unroll
        for (int j = 0; j < 4; ++j)
          acc[i][j] = fmaf(av[i], bv[j], acc[i][j]);
    }
    __syncthreads();
  }
  #pragma unroll
  for (int i = 0; i < 4; ++i) {
    int row = bm + tm + i;
    #pragma unroll
    for (int j = 0; j < 4; ++j) {
      int col = bn + tn + j;
      C[(size_t)row * kDM + col] =
          acc[i][j] + bias[col] + pos[(size_t)(row & 255) * kDM + col];
    }
  }
}

// ------------- layernorm over DM=384; bf16 out; optionally zero proj -------
template <bool BF16OUT>
__global__ __launch_bounds__(384) void ln_k(
    const float* __restrict__ in, void* __restrict__ outv,
    const float* __restrict__ g, const float* __restrict__ bb,
    float* __restrict__ proj_zero) {
  int t = blockIdx.x, d = threadIdx.x;
  if (proj_zero && d < kPROJ) proj_zero[(size_t)t * kPROJ + d] = 0.f;
  float v = in[(size_t)t * kDM + d];
  float s = v, s2 = v * v;
  #pragma unroll
  for (int m = 32; m >= 1; m >>= 1) {
    s  += __shfl_xor(s, m);
    s2 += __shfl_xor(s2, m);
  }
  __shared__ float ps[6], ps2[6];
  if ((d & 63) == 0) { ps[d >> 6] = s; ps2[d >> 6] = s2; }
  __syncthreads();
  float S = 0.f, S2 = 0.f;
  #pragma unroll
  for (int i = 0; i < 6; ++i) { S += ps[i]; S2 += ps2[i]; }
  float mean = S * (1.f / 384.f);
  float var  = S2 * (1.f / 384.f) - mean * mean;
  float r = rsqrtf(var + 1e-5f);
  float o = (v - mean) * r * g[d] + bb[d];
  if (BF16OUT) ((unsigned short*)outv)[(size_t)t * kDM + d] = f2bf(o);
  else ((float*)outv)[(size_t)t * kDM + d] = o;
}

// ------------- convert ALL layers' GEMM weights fp32 -> bf16 ---------------
// dst layout per layer: [in (589824) | out (294912) | x (43008)]
__global__ __launch_bounds__(256) void convert_all_k(
    const float* __restrict__ w_in, const float* __restrict__ w_out,
    const float* __restrict__ w_x, unsigned short* __restrict__ dst) {
  int layer = blockIdx.y;
  int i4 = (blockIdx.x * 256 + threadIdx.x) * 4;
  if (i4 >= kWTOT) return;
  const float* src;
  int off;
  if (i4 < kWIN) { src = w_in + (size_t)layer * kWIN; off = i4; }
  else if (i4 < kWIN + kWOUT) { src = w_out + (size_t)layer * kWOUT; off = i4 - kWIN; }
  else { src = w_x + (size_t)layer * kWX; off = i4 - kWIN - kWOUT; }
  float4 v = *(const float4*)(src + off);
  unsigned short o[4] = {f2bf(v.x), f2bf(v.y), f2bf(v.z), f2bf(v.w)};
  *(uint2*)(dst + (size_t)layer * kWTOT + i4) = *(const uint2*)o;
}

// ------------- bf16 MFMA NT GEMM: C[M,N] fp32 = A[M,K]·B[N,K]^T ------------
// BM=128, BK=32, 256 threads (4 waves). BN in {64,128}.
// EPIL 0: plain store. EPIL 1: atomicAdd with col<N guard (split-K / residual).
template <int BN, int EPIL>
__global__ __launch_bounds__(256) void bgemm_k(
    const unsigned short* __restrict__ A, int lda,
    const unsigned short* __restrict__ B, int ldb,
    float* __restrict__ C, int ldc, int N, int Kc) {
  __shared__ __align__(16) unsigned short As[4][128][8];
  __shared__ __align__(16) unsigned short Bs[4][BN][8];
  int tid = threadIdx.x;
  int bm = blockIdx.y * 128;
  int bn = blockIdx.x * BN;
  int k_begin = blockIdx.z * Kc;
  int wave = tid >> 6, lane = tid & 63;
  int lm = lane & 15, lq = lane >> 4;
  int wm, wn;
  if (BN == 128) { wm = (wave >> 1) * 64; wn = (wave & 1) * 64; }
  else           { wm = wave * 32;        wn = 0; }
  constexpr int MT = (BN == 128) ? 4 : 2;
  f32x4 acc[MT][4] = {};

  for (int kt = 0; kt < Kc; kt += 32) {
    int k0 = k_begin + kt;
    int ar0 = tid & 127, aq0 = tid >> 7;
    int aq1 = aq0 + 2;
    uint4 a0 = *(const uint4*)(A + (size_t)(bm + ar0) * lda + k0 + aq0 * 8);
    uint4 a1 = *(const uint4*)(A + (size_t)(bm + ar0) * lda + k0 + aq1 * 8);
    uint4 b0, b1;
    int br0, bq0, br1 = 0, bq1 = 0;
    if (BN == 128) {
      br0 = tid & 127; bq0 = tid >> 7; br1 = br0; bq1 = bq0 + 2;
      b0 = *(const uint4*)(B + (size_t)(bn + br0) * ldb + k0 + bq0 * 8);
      b1 = *(const uint4*)(B + (size_t)(bn + br1) * ldb + k0 + bq1 * 8);
    } else {
      br0 = tid & 63; bq0 = tid >> 6;
      if (bn + br0 < N)
        b0 = *(const uint4*)(B + (size_t)(bn + br0) * ldb + k0 + bq0 * 8);
      else
        b0 = make_uint4(0u, 0u, 0u, 0u);
    }
    __syncthreads();
    *(uint4*)&As[aq0][ar0][0] = a0;
    *(uint4*)&As[aq1][ar0][0] = a1;
    *(uint4*)&Bs[bq0][br0][0] = b0;
    if (BN == 128) *(uint4*)&Bs[bq1][br1][0] = b1;
    __syncthreads();

    short8 bfrag[4];
    #pragma unroll
    for (int ni = 0; ni < 4; ++ni)
      bfrag[ni] = *(const short8*)&Bs[lq][wn + ni * 16 + lm][0];
    #pragma unroll
    for (int mi = 0; mi < MT; ++mi) {
      short8 afrag = *(const short8*)&As[lq][wm + mi * 16 + lm][0];
      #pragma unroll
      for (int ni = 0; ni < 4; ++ni)
        acc[mi][ni] = __builtin_amdgcn_mfma_f32_16x16x32_bf16(
            afrag, bfrag[ni], acc[mi][ni], 0, 0, 0);
    }
  }

  #pragma unroll
  for (int mi = 0; mi < MT; ++mi) {
    #pragma unroll
    for (int ni = 0; ni < 4; ++ni) {
      int grow = bm + wm + mi * 16 + lq * 4;
      int gcol = bn + wn + ni * 16 + lm;
      float* cp = C + (size_t)grow * ldc + gcol;
      #pragma unroll
      for (int r = 0; r < 4; ++r) {
        float v = acc[mi][ni][r];
        if (EPIL == 0) {
          cp[(size_t)r * ldc] = v;
        } else {
          if (gcol < N) atomicAdd(cp + (size_t)r * ldc, v);
        }
      }
    }
  }
}

// ------------- causal depthwise conv (DC=4) + SiLU + z-gate ----------------
// writes uT[b][d][l] fp32, sgT[b][d][l]=silu(z) fp32, u_bf[token][d] bf16
__global__ __launch_bounds__(256) void conv_tr_k(
    const float* __restrict__ xz, const float* __restrict__ cw,
    const float* __restrict__ cb, float* __restrict__ uT,
    float* __restrict__ sgT, unsigned short* __restrict__ u_bf) {
  int b = blockIdx.y;
  int l0 = blockIdx.x * 16;
  int tid = threadIdx.x;
  #pragma unroll
  for (int ch = 0; ch < 3; ++ch) {
    int d = ch * 256 + tid;
    float w0 = cw[d * 4], w1 = cw[d * 4 + 1], w2 = cw[d * 4 + 2], w3 = cw[d * 4 + 3];
    float bias = cb[d];
    float v[19];
    #pragma unroll
    for (int j = 0; j < 19; ++j) {
      int l = l0 - 3 + j;
      v[j] = (l >= 0) ? xz[(size_t)(b * kL + l) * (2 * kDI) + d] : 0.f;
    }
    float* up = uT + ((size_t)b * kDI + d) * kL + l0;
    float* sp = sgT + ((size_t)b * kDI + d) * kL + l0;
    #pragma unroll
    for (int i = 0; i < 16; ++i) {
      float acc = bias;
      acc = fmaf(v[i], w0, acc);
      acc = fmaf(v[i + 1], w1, acc);
      acc = fmaf(v[i + 2], w2, acc);
      acc = fmaf(v[i + 3], w3, acc);
      float o = silu_f(acc);
      up[i] = o;
      u_bf[(size_t)(b * kL + l0 + i) * kDI + d] = f2bf(o);
      float zv = xz[(size_t)(b * kL + l0 + i) * (2 * kDI) + kDI + d];
      sp[i] = silu_f(zv);
    }
  }
}

// ------------- fused dt_proj + chunked selective scan ----------------------
// One block per (b,d); 256 threads = (chunk c, state n). Thread tid also
// computes delta[l=tid] = softplus(proj[b,l,0:24]·Wdt[d,:] + bdt[d]).
__global__ __launch_bounds__(256) void scan2_k(
    const float* __restrict__ proj, const float* __restrict__ uT,
    const float* __restrict__ sgT, const float* __restrict__ dtw,
    const float* __restrict__ dtb, const float* __restrict__ A_log,
    const float* __restrict__ Dsk, float* __restrict__ yT) {
  int d = blockIdx.x;   // 0..767
  int b = blockIdx.y;   // 0..7
  int tid = threadIdx.x;
  int c = tid >> 4;     // chunk
  int n = tid & 15;     // state
  __shared__ float sd[256], su[256], sg[256], sy[256];
  __shared__ float sh_h[16][17], sh_a[16][17];
  __shared__ float swdt[24];
  size_t rbase = ((size_t)b * kDI + d) * kL;
  su[tid] = uT[rbase + tid];
  sg[tid] = sgT[rbase + tid];
  if (tid < kDTR) swdt[tid] = dtw[(size_t)d * kDTR + tid];
  float bdt = dtb[d];
  float Aval = -__expf(A_log[d * kDS + n]);
  __syncthreads();
  // delta for l = tid
  {
    const float* pr = proj + (size_t)(b * kL + tid) * kPROJ;
    float acc = bdt;
    #pragma unroll
    for (int r4 = 0; r4 < 6; ++r4) {
      float4 pv = *(const float4*)(pr + r4 * 4);
      acc = fmaf(pv.x, swdt[r4 * 4 + 0], acc);
      acc = fmaf(pv.y, swdt[r4 * 4 + 1], acc);
      acc = fmaf(pv.z, swdt[r4 * 4 + 2], acc);
      acc = fmaf(pv.w, swdt[r4 * 4 + 3], acc);
    }
    sd[tid] = softplus_f(acc);
  }
  __syncthreads();

  float h = 0.f, ca = 1.f;
  float h_reg[16], ca_reg[16], cv[16];
  const float* pp = proj + (size_t)(b * kL + c * 16) * kPROJ;
  #pragma unroll
  for (int i = 0; i < 16; ++i) {
    int l = c * 16 + i;
    float dl = sd[l], uv = su[l];
    float Bv = pp[i * kPROJ + kDTR + n];
    cv[i] = pp[i * kPROJ + kDTR + kDS + n];
    float a = __expf(dl * Aval);
    h = fmaf(a, h, (dl * uv) * Bv);
    ca *= a;
    h_reg[i] = h;
    ca_reg[i] = ca;
  }
  sh_h[c][n] = h;
  sh_a[c][n] = ca;
  __syncthreads();

  float h0 = 0.f;
  for (int j = 0; j < c; ++j) h0 = fmaf(sh_a[j][n], h0, sh_h[j][n]);

  float Dv = Dsk[d];
  #pragma unroll
  for (int i = 0; i < 16; ++i) {
    int l = c * 16 + i;
    float yv = fmaf(ca_reg[i], h0, h_reg[i]) * cv[i];
    yv += __shfl_xor(yv, 1);
    yv += __shfl_xor(yv, 2);
    yv += __shfl_xor(yv, 4);
    yv += __shfl_xor(yv, 8);
    if (n == 0) sy[l] = (yv + su[l] * Dv) * sg[l];
  }
  __syncthreads();
  yT[rbase + tid] = sy[tid];
}

// ------------- transpose yT [b][768][256] fp32 -> y_bf [2048][768] bf16 ----
__global__ __launch_bounds__(256) void transpose_bf_k(
    const float* __restrict__ yT, unsigned short* __restrict__ ybf) {
  int b = blockIdx.z;
  int db = blockIdx.y;   // 12 tiles of 64 d
  int lb = blockIdx.x;   // 4 tiles of 64 l
  __shared__ float tile[64][65];
  int tid = threadIdx.x;
  int lx = tid & 63, dq = tid >> 6;
  const float* src = yT + ((size_t)b * kDI + db * 64) * kL + lb * 64;
  #pragma unroll
  for (int i = 0; i < 16; ++i) {
    int d = dq * 16 + i;
    tile[d][lx] = src[(size_t)d * kL + lx];
  }
  __syncthreads();
  int ly = tid >> 2, dx0 = (tid & 3) * 16;
  unsigned short tmp[16];
  #pragma unroll
  for (int i = 0; i < 16; ++i) tmp[i] = f2bf(tile[dx0 + i][ly]);
  unsigned short* dst =
      ybf + (size_t)(b * kL + lb * 64 + ly) * kDI + db * 64 + dx0;
  *(uint4*)dst = *(const uint4*)tmp;
  *(uint4*)(dst + 8) = *(const uint4*)(tmp + 8);
}

// ---------------- mean pool over L ----------------
__global__ __launch_bounds__(384) void pool_k(
    const float* __restrict__ h, float* __restrict__ pooled) {
  int b = blockIdx.x, d = threadIdx.x;
  float acc = 0.f;
  for (int l = 0; l < kL; ++l) acc += h[(size_t)(b * kL + l) * kDM + d];
  pooled[b * kDM + d] = acc * (1.f / 256.f);
}

// ---------------- head ----------------
__global__ __launch_bounds__(64) void head_k(
    const float* __restrict__ pooled, const float* __restrict__ hw,
    const float* __restrict__ hb, float* __restrict__ out) {
  int b = blockIdx.x >> 2, c = blockIdx.x & 3;
  int lane = threadIdx.x;
  float acc = 0.f;
  for (int dd = lane; dd < kDM; dd += 64)
    acc = fmaf(pooled[b * kDM + dd], hw[c * kDM + dd], acc);
  #pragma unroll
  for (int m = 32; m >= 1; m >>= 1) acc += __shfl_xor(acc, m);
  if (lane == 0) out[b * 4 + c] = acc + hb[c];
}

}  // namespace

extern "C" void kernel_launch(void* const* d_in, const int* in_sizes, int n_in,
                              void* d_out, int out_size, void* d_ws, size_t ws_size,
                              hipStream_t stream) {
  (void)in_sizes; (void)n_in; (void)out_size; (void)ws_size;
  const float* x        = (const float*)d_in[0];
  const float* patch_w  = (const float*)d_in[1];
  const float* patch_b  = (const float*)d_in[2];
  const float* pos      = (const float*)d_in[3];
  const float* ln_g     = (const float*)d_in[4];
  const float* ln_b     = (const float*)d_in[5];
  const float* in_w     = (const float*)d_in[6];
  const float* conv_w   = (const float*)d_in[7];
  const float* conv_b   = (const float*)d_in[8];
  const float* xproj_w  = (const float*)d_in[9];
  const float* dtproj_w = (const float*)d_in[10];
  const float* dtproj_b = (const float*)d_in[11];
  const float* A_log    = (const float*)d_in[12];
  const float* Dskip    = (const float*)d_in[13];
  const float* out_w    = (const float*)d_in[14];
  const float* fn_g     = (const float*)d_in[15];
  const float* fn_b     = (const float*)d_in[16];
  const float* head_w   = (const float*)d_in[17];
  const float* head_b   = (const float*)d_in[18];
  float* out = (float*)d_out;

  float* ws = (float*)d_ws;
  float* tok    = ws; ws += kTok * kDM;       // fp32 residual
  float* xz     = ws; ws += kTok * 2 * kDI;
  float* uT     = ws; ws += kTok * kDI;
  float* sgT    = ws; ws += kTok * kDI;
  float* proj   = ws; ws += kTok * kPROJ;
  float* yT     = ws; ws += kTok * kDI;
  float* pooled = ws; ws += kB * kDM;
  unsigned short* h_bf = (unsigned short*)ws; ws += kTok * kDM / 2;
  unsigned short* y_bf = (unsigned short*)ws; ws += kTok * kDI / 2;
  unsigned short* u_bf = (unsigned short*)ws; ws += kTok * kDI / 2;
  unsigned short* w_bf = (unsigned short*)ws; ws += (size_t)kNL * kWTOT / 2;
  float* lnout = yT;  // overlay: yT dead after last transpose

  // all-layer weight cast (once per call)
  convert_all_k<<<dim3(kWTOT / 4 / 256, kNL), 256, 0, stream>>>(
      in_w, out_w, xproj_w, w_bf);

  // Patch embedding fused: im2col + GEMM + bias + pos
  patch_gemm_k<<<dim3(6, 32), 256, 0, stream>>>(x, patch_w, patch_b, pos, tok);

  for (int layer = 0; layer < kNL; ++layer) {
    const unsigned short* wl = w_bf + (size_t)layer * kWTOT;
    // LN -> bf16 A operand; also zeroes proj for this layer's split-K GEMM
    ln_k<true><<<kTok, kDM, 0, stream>>>(tok, h_bf, ln_g + layer * kDM,
                                         ln_b + layer * kDM, proj);
    // in_proj (MFMA): [2048,384]x[1536,384]^T -> xz fp32
    bgemm_k<128, 0><<<dim3(12, 16, 1), 256, 0, stream>>>(
        h_bf, kDM, wl, kDM, xz, 2 * kDI, 2 * kDI, kDM);
    // depthwise causal conv + SiLU + z-gate -> uT, sgT fp32; u_bf bf16
    conv_tr_k<<<dim3(16, kB), 256, 0, stream>>>(
        xz, conv_w + layer * kDI * 4, conv_b + layer * kDI, uT, sgT, u_bf);
    // x_proj (MFMA, split-K=6, atomic): [2048,768]x[56,768]^T -> proj
    bgemm_k<64, 1><<<dim3(1, 16, 6), 256, 0, stream>>>(
        u_bf, kDI, wl + kWIN + kWOUT, kDI, proj, kPROJ, kPROJ, kDI / 6);
    // fused dt_proj + selective scan + skip + gate -> yT
    scan2_k<<<dim3(kDI, kB), 256, 0, stream>>>(
        proj, uT, sgT, dtproj_w + (size_t)layer * kDI * kDTR,
        dtproj_b + layer * kDI, A_log + (size_t)layer * kDI * kDS,
        Dskip + layer * kDI, yT);
    // transpose+cast yT -> y_bf [2048,768] bf16
    transpose_bf_k<<<dim3(4, 12, kB), 256, 0, stream>>>(yT, y_bf);
    // out_proj (MFMA, split-K=2, atomic into residual): tok += y x W^T
    bgemm_k<128, 1><<<dim3(3, 16, 2), 256, 0, stream>>>(
        y_bf, kDI, wl + kWIN, kDI, tok, kDM, kDM, kDI / 2);
  }

  ln_k<false><<<kTok, kDM, 0, stream>>>(tok, lnout, fn_g, fn_b, nullptr);
  pool_k<<<kB, kDM, 0, stream>>>(lnout, pooled);
  head_k<<<kB * 4, 64, 0, stream>>>(pooled, head_w, head_b, out);
}